// Round 2
// baseline (701.644 us; speedup 1.0000x reference)
//
#include <hip/hip_runtime.h>
#include <stdint.h>

// KVCacheAttention prefill, MI355X. Round 2: hardened correctness-first MFMA pipeline.
// Precision: split-bf16 (3-pass) for K/V projections (validated cache outputs),
// single-bf16 for Q/O projections and attention core.
// ws requirement: 142,606,336 B (136 MB).

typedef unsigned short u16;
typedef __attribute__((ext_vector_type(8))) short s16x8;  // 8 bf16 bits (guide-verified operand type)
typedef __attribute__((ext_vector_type(4))) float f32x4;

#define DM 2048
#define NH 16
#define DK 128
#define SN 1024
#define SC 3072
#define ST 4096

__device__ __forceinline__ u16 bf16rn(float x) {
  uint32_t u = __float_as_uint(x);
  return (u16)((u + 0x7FFFu + ((u >> 16) & 1u)) >> 16);
}
__device__ __forceinline__ float bf16f(u16 h) {
  return __uint_as_float(((uint32_t)h) << 16);
}
__device__ __forceinline__ s16x8 ldfrag(const u16* p) {
  union { uint4 u; s16x8 v; } c;
  c.u = *(const uint4*)p;
  return c.v;
}
__device__ __forceinline__ f32x4 mfma16(s16x8 a, s16x8 b, f32x4 c) {
  return __builtin_amdgcn_mfma_f32_16x16x32_bf16(a, b, c, 0, 0, 0);
}
__device__ __forceinline__ void gload16(const u16* g, u16* l) {
  __builtin_amdgcn_global_load_lds(
      (const __attribute__((address_space(1))) void*)g,
      (__attribute__((address_space(3))) void*)l, 16, 0, 0);
}

// ---------------- pack: f32 -> bf16 hi (+ optional lo residual) ----------------
__global__ void pack_kernel(const float* __restrict__ src, u16* __restrict__ hi,
                            u16* __restrict__ lo, int n4) {
  int stride = gridDim.x * blockDim.x;
  for (int i = blockIdx.x * blockDim.x + threadIdx.x; i < n4; i += stride) {
    float4 v = ((const float4*)src)[i];
    u16 h0 = bf16rn(v.x), h1 = bf16rn(v.y), h2 = bf16rn(v.z), h3 = bf16rn(v.w);
    ushort4 H; H.x = h0; H.y = h1; H.z = h2; H.w = h3;
    ((ushort4*)hi)[i] = H;
    if (lo) {
      ushort4 L;
      L.x = bf16rn(v.x - bf16f(h0));
      L.y = bf16rn(v.y - bf16f(h1));
      L.z = bf16rn(v.z - bf16f(h2));
      L.w = bf16rn(v.w - bf16f(h3));
      ((ushort4*)lo)[i] = L;
    }
  }
}

// ---------------- old K cache: fp32 copy + bf16 copy ----------------
__global__ void cache_k_kernel(const float* __restrict__ src, float* __restrict__ dstf,
                               u16* __restrict__ k_all) {
  const int total = 2 * NH * SC * DK / 4;  // float4 count
  int stride = gridDim.x * blockDim.x;
  for (int i = blockIdx.x * blockDim.x + threadIdx.x; i < total; i += stride) {
    int bh = i / (SC * DK / 4);
    int rem = i - bh * (SC * DK / 4);
    float4 v = ((const float4*)src)[i];
    size_t d = (size_t)bh * (ST * DK / 4) + rem;
    ((float4*)dstf)[d] = v;
    ushort4 hh;
    hh.x = bf16rn(v.x); hh.y = bf16rn(v.y); hh.z = bf16rn(v.z); hh.w = bf16rn(v.w);
    ((ushort4*)k_all)[d] = hh;
  }
}

// ---------------- old V cache: fp32 copy + bf16 TRANSPOSED copy (V_t[d][j]) ----------------
__global__ void cache_v_kernel(const float* __restrict__ src, float* __restrict__ dstf,
                               u16* __restrict__ v_t) {
  const int jt = blockIdx.x, h = blockIdx.y, b = blockIdx.z;
  const int bh = b * NH + h;
  const float* s = src + (size_t)bh * SC * DK + (size_t)jt * 64 * DK;
  float* df = dstf + (size_t)bh * ST * DK + (size_t)jt * 64 * DK;
  u16* dt = v_t + (size_t)bh * DK * ST + jt * 64;
  __shared__ u16 tr[DK * 64];  // [d][64 j], XOR-swizzled 16B granules
  const int t = threadIdx.x;
  const int d = t & 127, jg = t >> 7;
  u16 tmp[32];
#pragma unroll
  for (int jj = 0; jj < 32; ++jj) {
    int j = jg * 32 + jj;
    float v = s[j * DK + d];
    df[j * DK + d] = v;
    tmp[jj] = bf16rn(v);
  }
#pragma unroll
  for (int c = 0; c < 4; ++c) {
    int gc = jg * 4 + c;
    int gcs = gc ^ (d & 7);
    uint4 w;
    w.x = (uint32_t)tmp[c * 8 + 0] | ((uint32_t)tmp[c * 8 + 1] << 16);
    w.y = (uint32_t)tmp[c * 8 + 2] | ((uint32_t)tmp[c * 8 + 3] << 16);
    w.z = (uint32_t)tmp[c * 8 + 4] | ((uint32_t)tmp[c * 8 + 5] << 16);
    w.w = (uint32_t)tmp[c * 8 + 6] | ((uint32_t)tmp[c * 8 + 7] << 16);
    ((uint4*)tr)[d * 8 + gcs] = w;
  }
  __syncthreads();
#pragma unroll
  for (int it = 0; it < 4; ++it) {
    int d2 = it * 32 + (t >> 3);
    int gc = t & 7;
    int gcs = gc ^ (d2 & 7);
    uint4 v = ((const uint4*)tr)[d2 * 8 + gcs];
    *(uint4*)(dt + (size_t)d2 * ST + gc * 8) = v;
  }
}

// ---------------- GEMM y = A @ W^T + bias (A,W row-major along K=2048) ----------------
// MODE 0: fused QKV (blockIdx.y>>4 selects proj; K/V use hi/lo split, 3 MFMA passes)
// MODE 1: O-projection (single pass, fp32 out)
template <int MODE>
__launch_bounds__(256)
__global__ void gemm_kernel(const u16* __restrict__ Ahi, const u16* __restrict__ Alo,
                            const u16* __restrict__ B0, const u16* __restrict__ B1h,
                            const u16* __restrict__ B1l, const u16* __restrict__ B2h,
                            const u16* __restrict__ B2l,
                            const float* __restrict__ bias0, const float* __restrict__ bias1,
                            const float* __restrict__ bias2,
                            u16* __restrict__ q_bf, float* __restrict__ cacheK,
                            u16* __restrict__ k_all, float* __restrict__ cacheV,
                            u16* __restrict__ v_t, float* __restrict__ outO) {
  const int m0 = blockIdx.x * 128;
  int proj, n0;
  if (MODE == 0) { proj = blockIdx.y >> 4; n0 = (blockIdx.y & 15) * 128; }
  else           { proj = 0;               n0 = blockIdx.y * 128; }
  const bool SPLIT = (MODE == 0) && (proj != 0);
  const u16* Bh = (MODE == 1) ? B0 : (proj == 0 ? B0 : (proj == 1 ? B1h : B2h));
  const u16* Bl = (proj == 1) ? B1l : B2l;
  const float* bias = (MODE == 1) ? bias0 : (proj == 0 ? bias0 : (proj == 1 ? bias1 : bias2));

  __shared__ u16 lds[4 * 8192];  // tiles: Ahi | Alo | Bhi | Blo, each 128x64 bf16

  const int t = threadIdx.x;
  const int w = t >> 6;
  const int lane = t & 63, l15 = lane & 15, l4 = lane >> 4;
  const int wr = w >> 1, wc = w & 1;

  f32x4 acc[4][4] = {};

  int srow[4], sgsw[4];
#pragma unroll
  for (int i = 0; i < 4; ++i) {
    int G = i * 256 + t;
    srow[i] = G >> 3;
    sgsw[i] = (G & 7) ^ (srow[i] & 7);  // pre-swizzled source granule (m173 pattern)
  }
  const int ldst = w * 512;  // wave-uniform LDS base (u16 units)

  for (int kk = 0; kk < 2048; kk += 64) {
#pragma unroll
    for (int i = 0; i < 4; ++i) {
      const size_t ao = (size_t)(m0 + srow[i]) * 2048 + kk + sgsw[i] * 8;
      const size_t bo_ = (size_t)(n0 + srow[i]) * 2048 + kk + sgsw[i] * 8;
      u16* ld = lds + i * 2048 + ldst;
      gload16(Ahi + ao, ld);
      gload16(Bh + bo_, ld + 16384);
      if (SPLIT) {
        gload16(Alo + ao, ld + 8192);
        gload16(Bl + bo_, ld + 24576);
      }
    }
    __syncthreads();
#pragma unroll
    for (int ks = 0; ks < 2; ++ks) {
      s16x8 ah[4], al[4], bh[4], bl[4];
#pragma unroll
      for (int f = 0; f < 4; ++f) {
        int ra = wr * 64 + f * 16 + l15;
        int off_a = ra * 64 + (((ks * 4 + l4) ^ (ra & 7)) * 8);
        ah[f] = ldfrag(lds + off_a);
        if (SPLIT) al[f] = ldfrag(lds + 8192 + off_a);
        int rb = wc * 64 + f * 16 + l15;
        int off_b = rb * 64 + (((ks * 4 + l4) ^ (rb & 7)) * 8);
        bh[f] = ldfrag(lds + 16384 + off_b);
        if (SPLIT) bl[f] = ldfrag(lds + 24576 + off_b);
      }
#pragma unroll
      for (int mf = 0; mf < 4; ++mf)
#pragma unroll
        for (int nf = 0; nf < 4; ++nf) {
          acc[mf][nf] = mfma16(ah[mf], bh[nf], acc[mf][nf]);
          if (SPLIT) {
            acc[mf][nf] = mfma16(ah[mf], bl[nf], acc[mf][nf]);
            acc[mf][nf] = mfma16(al[mf], bh[nf], acc[mf][nf]);
          }
        }
    }
    __syncthreads();
  }
  // epilogue: C/D layout col=lane&15, row=(lane>>4)*4+reg (m89-verified)
#pragma unroll
  for (int nf = 0; nf < 4; ++nf) {
    const int n = n0 + wc * 64 + nf * 16 + l15;
    const float bv_ = bias[n];
#pragma unroll
    for (int mf = 0; mf < 4; ++mf) {
#pragma unroll
      for (int r = 0; r < 4; ++r) {
        const int m = m0 + wr * 64 + mf * 16 + l4 * 4 + r;
        const float val = acc[mf][nf][r] + bv_;
        if (MODE == 1) {
          outO[(size_t)m * 2048 + n] = val;
        } else if (proj == 0) {
          const int b = m >> 10, ss = m & 1023, hh = n >> 7, d = n & 127;
          q_bf[(((size_t)(b * NH + hh)) * SN + ss) * DK + d] = bf16rn(val);
        } else {
          const int b = m >> 10, ss = m & 1023, hh = n >> 7, d = n & 127;
          const size_t idx = (((size_t)(b * NH + hh)) * ST + SC + ss) * DK + d;
          if (proj == 1) {
            cacheK[idx] = val;
            k_all[idx] = bf16rn(val);
          } else {
            cacheV[idx] = val;
            v_t[(((size_t)(b * NH + hh)) * DK + d) * ST + SC + ss] = bf16rn(val);
          }
        }
      }
    }
  }
}

// ---------------- flash attention: Q-tile 128 (8 waves x 16 rows), KV-tile 64 ----------------
__launch_bounds__(512)
__global__ void attn_kernel(const u16* __restrict__ q_bf, const u16* __restrict__ k_all,
                            const u16* __restrict__ v_t, u16* __restrict__ att) {
  const int qt = blockIdx.x, h = blockIdx.y, b = blockIdx.z;
  const int bh = b * NH + h;
  const int qb = qt * 128;
  __shared__ u16 Kt[64 * DK];   // [j][d] swizzled
  __shared__ u16 Vt[DK * 64];   // [d][j] swizzled
  __shared__ u16 Pl[128 * 64];  // [q][j] swizzled, wave-private rows
  const int t = threadIdx.x;
  const int w = t >> 6, lane = t & 63, l15 = lane & 15, l4 = lane >> 4;

  const u16* qbase = q_bf + (size_t)bh * SN * DK;
  s16x8 qf[4];
  {
    const int row = qb + w * 16 + l15;
#pragma unroll
    for (int ks = 0; ks < 4; ++ks)
      qf[ks] = ldfrag(qbase + (size_t)row * DK + ks * 32 + l4 * 8);
  }
  f32x4 o[8] = {};
  float mrow[4], lrow[4];
#pragma unroll
  for (int r = 0; r < 4; ++r) { mrow[r] = -1e30f; lrow[r] = 0.0f; }

  const u16* kbase = k_all + (size_t)bh * ST * DK;
  const u16* vbase = v_t + (size_t)bh * DK * ST;
  const int ntiles = ((qb + SC + 126) >> 6) + 1;  // covers j <= qb+127+3071

  for (int tile = 0; tile < ntiles; ++tile) {
    const int j0 = tile * 64;
#pragma unroll
    for (int i = 0; i < 2; ++i) {
      {
        const int G = i * 512 + t;
        const int row = G >> 4, gc = G & 15;
        gload16(kbase + (size_t)(j0 + row) * DK + ((gc ^ (row & 7)) * 8),
                Kt + (i * 512 + w * 64) * 8);
      }
      {
        const int G = i * 512 + t;
        const int row = G >> 3, gc = G & 7;
        gload16(vbase + (size_t)row * ST + j0 + ((gc ^ (row & 7)) * 8),
                Vt + (i * 512 + w * 64) * 8);
      }
    }
    __syncthreads();
    // QK^T
    f32x4 sc[4] = {};
#pragma unroll
    for (int ks = 0; ks < 4; ++ks) {
#pragma unroll
      for (int nf = 0; nf < 4; ++nf) {
        const int j = nf * 16 + l15;
        s16x8 kf = ldfrag(Kt + j * DK + (((ks * 4 + l4) ^ (j & 7)) * 8));
        sc[nf] = mfma16(qf[ks], kf, sc[nf]);
      }
    }
    const bool domask = (j0 + 63) >= (qb + SC);
    const float sscale = 0.08838834764831845f;  // 1/sqrt(128)
    float tmax[4];
#pragma unroll
    for (int r = 0; r < 4; ++r) tmax[r] = -1e30f;
#pragma unroll
    for (int nf = 0; nf < 4; ++nf) {
#pragma unroll
      for (int r = 0; r < 4; ++r) {
        float s_ = sc[nf][r] * sscale;
        if (domask) {
          const int j = j0 + nf * 16 + l15;
          const int q = qb + w * 16 + l4 * 4 + r;
          if (j >= q + SC) s_ = -1e30f;  // reference masks j >= q+3072 (self excluded)
        }
        sc[nf][r] = s_;
        tmax[r] = fmaxf(tmax[r], s_);
      }
    }
#pragma unroll
    for (int mk = 1; mk < 16; mk <<= 1)
#pragma unroll
      for (int r = 0; r < 4; ++r)
        tmax[r] = fmaxf(tmax[r], __shfl_xor(tmax[r], mk, 64));
    float so[4], rs[4];
#pragma unroll
    for (int r = 0; r < 4; ++r) {
      const float mn = fmaxf(mrow[r], tmax[r]);
      so[r] = __expf(mrow[r] - mn);
      mrow[r] = mn;
      rs[r] = 0.0f;
    }
#pragma unroll
    for (int nf = 0; nf < 4; ++nf) {
#pragma unroll
      for (int r = 0; r < 4; ++r) {
        const float p = __expf(sc[nf][r] - mrow[r]);
        rs[r] += p;
        const int qrow = w * 16 + l4 * 4 + r;
        const int jl = nf * 16 + l15;
        Pl[qrow * 64 + ((((jl >> 3) ^ (qrow & 7)) << 3) | (jl & 7))] = bf16rn(p);
      }
    }
#pragma unroll
    for (int mk = 1; mk < 16; mk <<= 1)
#pragma unroll
      for (int r = 0; r < 4; ++r)
        rs[r] += __shfl_xor(rs[r], mk, 64);
#pragma unroll
    for (int r = 0; r < 4; ++r) lrow[r] = lrow[r] * so[r] + rs[r];
#pragma unroll
    for (int nf = 0; nf < 8; ++nf)
#pragma unroll
      for (int r = 0; r < 4; ++r) o[nf][r] *= so[r];
    asm volatile("s_waitcnt lgkmcnt(0)" ::: "memory");  // own-wave Pl writes visible
    // PV: O += P @ V  (A=P from Pl, B=V^T rows from Vt[d][j] -> contiguous b128)
#pragma unroll
    for (int ks = 0; ks < 2; ++ks) {
      const int qrow = w * 16 + l15;
      s16x8 pf = ldfrag(Pl + qrow * 64 + (((ks * 4 + l4) ^ (qrow & 7)) * 8));
#pragma unroll
      for (int nf = 0; nf < 8; ++nf) {
        const int d = nf * 16 + l15;
        s16x8 vf = ldfrag(Vt + d * 64 + (((ks * 4 + l4) ^ (d & 7)) * 8));
        o[nf] = mfma16(pf, vf, o[nf]);
      }
    }
    __syncthreads();
  }
  u16* ob = att + ((size_t)b * SN) * DM + (size_t)h * DK;
#pragma unroll
  for (int nf = 0; nf < 8; ++nf) {
#pragma unroll
    for (int r = 0; r < 4; ++r) {
      const int q = qb + w * 16 + l4 * 4 + r;
      const int d = nf * 16 + l15;
      ob[(size_t)q * DM + d] = bf16rn(o[nf][r] / lrow[r]);
    }
  }
}

// ---------------- host ----------------
extern "C" void kernel_launch(void* const* d_in, const int* in_sizes, int n_in,
                              void* d_out, int out_size, void* d_ws, size_t ws_size,
                              hipStream_t stream) {
  const float* x     = (const float*)d_in[0];
  const float* cache = (const float*)d_in[1];
  const float* Wq = (const float*)d_in[2];
  const float* bq = (const float*)d_in[3];
  const float* Wk = (const float*)d_in[4];
  const float* bk = (const float*)d_in[5];
  const float* Wv = (const float*)d_in[6];
  const float* bv = (const float*)d_in[7];
  const float* Wo = (const float*)d_in[8];
  const float* bo = (const float*)d_in[9];

  float* out = (float*)d_out;
  float* cacheK = out + (size_t)2 * SN * DM;           // +4,194,304 f32
  float* cacheV = cacheK + (size_t)2 * NH * ST * DK;   // +16,777,216 f32

  char* ws = (char*)d_ws;
  u16* x_hi  = (u16*)(ws + 0);
  u16* x_lo  = (u16*)(ws + 8388608ull);
  u16* wq_hi = (u16*)(ws + 16777216ull);
  u16* wk_hi = (u16*)(ws + 25165824ull);
  u16* wk_lo = (u16*)(ws + 33554432ull);
  u16* wv_hi = (u16*)(ws + 41943040ull);
  u16* wv_lo = (u16*)(ws + 50331648ull);
  u16* wo_hi = (u16*)(ws + 58720256ull);
  u16* q_bf  = (u16*)(ws + 67108864ull);
  u16* k_all = (u16*)(ws + 75497472ull);   // 33,554,432 B
  u16* v_t   = (u16*)(ws + 109051904ull);  // 33,554,432 B; total 142,606,336 B
  u16* att   = x_hi;  // reuse: x_hi dead after QKV GEMM, attn writes att after it

  const int W4 = 2048 * 2048 / 4;
  pack_kernel<<<2048, 256, 0, stream>>>(x,  x_hi,  x_lo,  W4);
  pack_kernel<<<2048, 256, 0, stream>>>(Wk, wk_hi, wk_lo, W4);
  pack_kernel<<<2048, 256, 0, stream>>>(Wv, wv_hi, wv_lo, W4);
  pack_kernel<<<2048, 256, 0, stream>>>(Wq, wq_hi, nullptr, W4);
  pack_kernel<<<2048, 256, 0, stream>>>(Wo, wo_hi, nullptr, W4);
  cache_k_kernel<<<4096, 256, 0, stream>>>(cache, cacheK, k_all);
  cache_v_kernel<<<dim3(SC / 64, NH, 2), 256, 0, stream>>>(
      cache + (size_t)2 * NH * SC * DK, cacheV, v_t);
  gemm_kernel<0><<<dim3(16, 48), 256, 0, stream>>>(
      x_hi, x_lo, wq_hi, wk_hi, wk_lo, wv_hi, wv_lo,
      bq, bk, bv, q_bf, cacheK, k_all, cacheV, v_t, nullptr);
  attn_kernel<<<dim3(8, NH, 2), 512, 0, stream>>>(q_bf, k_all, v_t, att);
  gemm_kernel<1><<<dim3(16, 16), 256, 0, stream>>>(
      att, nullptr, wo_hi, nullptr, nullptr, nullptr, nullptr,
      bo, nullptr, nullptr, nullptr, nullptr, nullptr, nullptr, nullptr, out);
}

// Round 3
// 626.524 us; speedup vs baseline: 1.1199x; 1.1199x over previous
//
#include <hip/hip_runtime.h>
#include <stdint.h>

// KVCacheAttention prefill, MI355X. Round 3: swapped-operand 32x32 flash attention
// (zero-LDS P path, double-buffered K/V, KV-split 2 + combine).
// Precision: split-bf16 (3-pass) for K/V projections, single-bf16 elsewhere.
// ws requirement: 142,606,336 B (136 MB), with dead-region reuse for partials.

typedef unsigned short u16;
typedef __attribute__((ext_vector_type(8))) short s16x8;   // 8 bf16 (4 VGPR)
typedef __attribute__((ext_vector_type(4))) float f32x4;
typedef __attribute__((ext_vector_type(16))) float f32x16;

#define DM 2048
#define NH 16
#define DK 128
#define SN 1024
#define SC 3072
#define ST 4096

__device__ __forceinline__ u16 bf16rn(float x) {
  uint32_t u = __float_as_uint(x);
  return (u16)((u + 0x7FFFu + ((u >> 16) & 1u)) >> 16);
}
__device__ __forceinline__ float bf16f(u16 h) {
  return __uint_as_float(((uint32_t)h) << 16);
}
__device__ __forceinline__ s16x8 ldfrag(const u16* p) {
  union { uint4 u; s16x8 v; } c;
  c.u = *(const uint4*)p;
  return c.v;
}
__device__ __forceinline__ f32x4 mfma16(s16x8 a, s16x8 b, f32x4 c) {
  return __builtin_amdgcn_mfma_f32_16x16x32_bf16(a, b, c, 0, 0, 0);
}
__device__ __forceinline__ f32x16 mfma32(s16x8 a, s16x8 b, f32x16 c) {
  return __builtin_amdgcn_mfma_f32_32x32x16_bf16(a, b, c, 0, 0, 0);
}
__device__ __forceinline__ void gload16(const u16* g, u16* l) {
  __builtin_amdgcn_global_load_lds(
      (const __attribute__((address_space(1))) void*)g,
      (__attribute__((address_space(3))) void*)l, 16, 0, 0);
}

// ---------------- pack: f32 -> bf16 hi (+ optional lo residual) ----------------
__global__ void pack_kernel(const float* __restrict__ src, u16* __restrict__ hi,
                            u16* __restrict__ lo, int n4) {
  int stride = gridDim.x * blockDim.x;
  for (int i = blockIdx.x * blockDim.x + threadIdx.x; i < n4; i += stride) {
    float4 v = ((const float4*)src)[i];
    u16 h0 = bf16rn(v.x), h1 = bf16rn(v.y), h2 = bf16rn(v.z), h3 = bf16rn(v.w);
    ushort4 H; H.x = h0; H.y = h1; H.z = h2; H.w = h3;
    ((ushort4*)hi)[i] = H;
    if (lo) {
      ushort4 L;
      L.x = bf16rn(v.x - bf16f(h0));
      L.y = bf16rn(v.y - bf16f(h1));
      L.z = bf16rn(v.z - bf16f(h2));
      L.w = bf16rn(v.w - bf16f(h3));
      ((ushort4*)lo)[i] = L;
    }
  }
}

// ---------------- old K cache: fp32 copy + bf16 copy ----------------
__global__ void cache_k_kernel(const float* __restrict__ src, float* __restrict__ dstf,
                               u16* __restrict__ k_all) {
  const int total = 2 * NH * SC * DK / 4;
  int stride = gridDim.x * blockDim.x;
  for (int i = blockIdx.x * blockDim.x + threadIdx.x; i < total; i += stride) {
    int bh = i / (SC * DK / 4);
    int rem = i - bh * (SC * DK / 4);
    float4 v = ((const float4*)src)[i];
    size_t d = (size_t)bh * (ST * DK / 4) + rem;
    ((float4*)dstf)[d] = v;
    ushort4 hh;
    hh.x = bf16rn(v.x); hh.y = bf16rn(v.y); hh.z = bf16rn(v.z); hh.w = bf16rn(v.w);
    ((ushort4*)k_all)[d] = hh;
  }
}

// ---------------- old V cache: fp32 copy + bf16 TRANSPOSED copy (V_t[d][j]) ----------------
__global__ void cache_v_kernel(const float* __restrict__ src, float* __restrict__ dstf,
                               u16* __restrict__ v_t) {
  const int jt = blockIdx.x, h = blockIdx.y, b = blockIdx.z;
  const int bh = b * NH + h;
  const float* s = src + (size_t)bh * SC * DK + (size_t)jt * 64 * DK;
  float* df = dstf + (size_t)bh * ST * DK + (size_t)jt * 64 * DK;
  u16* dt = v_t + (size_t)bh * DK * ST + jt * 64;
  __shared__ u16 tr[DK * 64];
  const int t = threadIdx.x;
  const int d = t & 127, jg = t >> 7;
  u16 tmp[32];
#pragma unroll
  for (int jj = 0; jj < 32; ++jj) {
    int j = jg * 32 + jj;
    float v = s[j * DK + d];
    df[j * DK + d] = v;
    tmp[jj] = bf16rn(v);
  }
#pragma unroll
  for (int c = 0; c < 4; ++c) {
    int gc = jg * 4 + c;
    int gcs = gc ^ (d & 7);
    uint4 w;
    w.x = (uint32_t)tmp[c * 8 + 0] | ((uint32_t)tmp[c * 8 + 1] << 16);
    w.y = (uint32_t)tmp[c * 8 + 2] | ((uint32_t)tmp[c * 8 + 3] << 16);
    w.z = (uint32_t)tmp[c * 8 + 4] | ((uint32_t)tmp[c * 8 + 5] << 16);
    w.w = (uint32_t)tmp[c * 8 + 6] | ((uint32_t)tmp[c * 8 + 7] << 16);
    ((uint4*)tr)[d * 8 + gcs] = w;
  }
  __syncthreads();
#pragma unroll
  for (int it = 0; it < 4; ++it) {
    int d2 = it * 32 + (t >> 3);
    int gc = t & 7;
    int gcs = gc ^ (d2 & 7);
    uint4 v = ((const uint4*)tr)[d2 * 8 + gcs];
    *(uint4*)(dt + (size_t)d2 * ST + gc * 8) = v;
  }
}

// ---------------- GEMM y = A @ W^T + bias ----------------
// MODE 0: fused QKV (Q output pre-scaled by 1/sqrt(dk)); MODE 1: O-projection
template <int MODE>
__launch_bounds__(256)
__global__ void gemm_kernel(const u16* __restrict__ Ahi, const u16* __restrict__ Alo,
                            const u16* __restrict__ B0, const u16* __restrict__ B1h,
                            const u16* __restrict__ B1l, const u16* __restrict__ B2h,
                            const u16* __restrict__ B2l,
                            const float* __restrict__ bias0, const float* __restrict__ bias1,
                            const float* __restrict__ bias2,
                            u16* __restrict__ q_bf, float* __restrict__ cacheK,
                            u16* __restrict__ k_all, float* __restrict__ cacheV,
                            u16* __restrict__ v_t, float* __restrict__ outO) {
  const int m0 = blockIdx.x * 128;
  int proj, n0;
  if (MODE == 0) { proj = blockIdx.y >> 4; n0 = (blockIdx.y & 15) * 128; }
  else           { proj = 0;               n0 = blockIdx.y * 128; }
  const bool SPLIT = (MODE == 0) && (proj != 0);
  const u16* Bh = (MODE == 1) ? B0 : (proj == 0 ? B0 : (proj == 1 ? B1h : B2h));
  const u16* Bl = (proj == 1) ? B1l : B2l;
  const float* bias = (MODE == 1) ? bias0 : (proj == 0 ? bias0 : (proj == 1 ? bias1 : bias2));

  __shared__ u16 lds[4 * 8192];

  const int t = threadIdx.x;
  const int w = t >> 6;
  const int lane = t & 63, l15 = lane & 15, l4 = lane >> 4;
  const int wr = w >> 1, wc = w & 1;

  f32x4 acc[4][4] = {};

  int srow[4], sgsw[4];
#pragma unroll
  for (int i = 0; i < 4; ++i) {
    int G = i * 256 + t;
    srow[i] = G >> 3;
    sgsw[i] = (G & 7) ^ (srow[i] & 7);
  }
  const int ldst = w * 512;

  for (int kk = 0; kk < 2048; kk += 64) {
#pragma unroll
    for (int i = 0; i < 4; ++i) {
      const size_t ao = (size_t)(m0 + srow[i]) * 2048 + kk + sgsw[i] * 8;
      const size_t bo_ = (size_t)(n0 + srow[i]) * 2048 + kk + sgsw[i] * 8;
      u16* ld = lds + i * 2048 + ldst;
      gload16(Ahi + ao, ld);
      gload16(Bh + bo_, ld + 16384);
      if (SPLIT) {
        gload16(Alo + ao, ld + 8192);
        gload16(Bl + bo_, ld + 24576);
      }
    }
    __syncthreads();
#pragma unroll
    for (int ks = 0; ks < 2; ++ks) {
      s16x8 ah[4], al[4], bh[4], bl[4];
#pragma unroll
      for (int f = 0; f < 4; ++f) {
        int ra = wr * 64 + f * 16 + l15;
        int off_a = ra * 64 + (((ks * 4 + l4) ^ (ra & 7)) * 8);
        ah[f] = ldfrag(lds + off_a);
        if (SPLIT) al[f] = ldfrag(lds + 8192 + off_a);
        int rb = wc * 64 + f * 16 + l15;
        int off_b = rb * 64 + (((ks * 4 + l4) ^ (rb & 7)) * 8);
        bh[f] = ldfrag(lds + 16384 + off_b);
        if (SPLIT) bl[f] = ldfrag(lds + 24576 + off_b);
      }
#pragma unroll
      for (int mf = 0; mf < 4; ++mf)
#pragma unroll
        for (int nf = 0; nf < 4; ++nf) {
          acc[mf][nf] = mfma16(ah[mf], bh[nf], acc[mf][nf]);
          if (SPLIT) {
            acc[mf][nf] = mfma16(ah[mf], bl[nf], acc[mf][nf]);
            acc[mf][nf] = mfma16(al[mf], bh[nf], acc[mf][nf]);
          }
        }
    }
    __syncthreads();
  }
#pragma unroll
  for (int nf = 0; nf < 4; ++nf) {
    const int n = n0 + wc * 64 + nf * 16 + l15;
    const float bv_ = bias[n];
#pragma unroll
    for (int mf = 0; mf < 4; ++mf) {
#pragma unroll
      for (int r = 0; r < 4; ++r) {
        const int m = m0 + wr * 64 + mf * 16 + l4 * 4 + r;
        const float val = acc[mf][nf][r] + bv_;
        if (MODE == 1) {
          outO[(size_t)m * 2048 + n] = val;
        } else if (proj == 0) {
          const int b = m >> 10, ss = m & 1023, hh = n >> 7, d = n & 127;
          // pre-scale Q by 1/sqrt(dk) so attention skips the per-score multiply
          q_bf[(((size_t)(b * NH + hh)) * SN + ss) * DK + d] =
              bf16rn(val * 0.08838834764831845f);
        } else {
          const int b = m >> 10, ss = m & 1023, hh = n >> 7, d = n & 127;
          const size_t idx = (((size_t)(b * NH + hh)) * ST + SC + ss) * DK + d;
          if (proj == 1) {
            cacheK[idx] = val;
            k_all[idx] = bf16rn(val);
          } else {
            cacheV[idx] = val;
            v_t[(((size_t)(b * NH + hh)) * DK + d) * ST + SC + ss] = bf16rn(val);
          }
        }
      }
    }
  }
}

// ---------------- flash attention: swapped-operand 32x32, KV-split 2 ----------------
// Block: 256 thr (4 waves), each wave owns 32 q rows (QBLK=128). KV tile 64,
// double-buffered (64KB LDS). S^T = mfma(K, Q); O^T = mfma(V^T, P^T); the P
// hand-off is in-register (one shfl_xor(32) pair per kt) -- no P LDS at all.
__launch_bounds__(256, 2)
__global__ void attn_kernel(const u16* __restrict__ q_bf, const u16* __restrict__ k_all,
                            const u16* __restrict__ v_t, float* __restrict__ op,
                            float* __restrict__ ml) {
  const int qt = blockIdx.x, h = blockIdx.y;
  const int b = blockIdx.z & 1, sp = blockIdx.z >> 1;
  const int bh = b * NH + h;
  const int qb = qt * 128;
  __shared__ u16 lds[2 * 16384];  // [buf][ Kt 64x128 | Vt 128x64 ]
  const int t = threadIdx.x;
  const int w = t >> 6, lane = t & 63;
  const int l31 = lane & 31, hi = lane >> 5;
  const int q = qb + w * 32 + l31;

  // Q fragments (B-operand: lane holds Q[q][kk*16 + hi*8 .. +7]); pre-scaled.
  s16x8 qf[8];
  {
    const u16* qrow = q_bf + ((size_t)bh * SN + q) * DK;
#pragma unroll
    for (int kk = 0; kk < 8; ++kk) qf[kk] = ldfrag(qrow + kk * 16 + hi * 8);
  }

  f32x16 o[4] = {};   // O^T[128 d][32 q]: o[dt], rows d = dt*32 + (r&3)+8*(r>>2)+4*hi
  float mrow = -1e30f, lrow = 0.f;

  const u16* kbase = k_all + (size_t)bh * ST * DK;
  const u16* vbase = v_t + (size_t)bh * DK * ST;
  const int ntiles = ((qb + 127 + SC - 1) >> 6) + 1;
  const int ntp = (ntiles + 1) >> 1;
  const int tile0 = sp * ntp;
  const int tile1 = min(ntiles, tile0 + ntp);

#define STAGE(buf, tile)                                                          \
  do {                                                                            \
    const int j0s = (tile) * 64;                                                  \
    u16* kt_ = lds + (buf) * 16384;                                               \
    u16* vt_ = lds + (buf) * 16384 + 8192;                                        \
    _Pragma("unroll")                                                             \
    for (int i = 0; i < 4; ++i) {                                                 \
      const int G = i * 256 + t;                                                  \
      const int krow = G >> 4, kgc = G & 15;                                      \
      gload16(kbase + (size_t)(j0s + krow) * DK + ((kgc ^ (krow & 15)) * 8),      \
              kt_ + (i * 256 + w * 64) * 8);                                      \
      const int vrow = G >> 3, vgc = G & 7;                                       \
      gload16(vbase + (size_t)vrow * ST + j0s + ((vgc ^ (vrow & 7)) * 8),         \
              vt_ + (i * 256 + w * 64) * 8);                                      \
    }                                                                             \
  } while (0)

  STAGE(0, tile0);
  __syncthreads();

  for (int tt = tile0; tt < tile1; ++tt) {
    const int cur = (tt - tile0) & 1;
    if (tt + 1 < tile1) STAGE(cur ^ 1, tt + 1);
    const u16* kt = lds + cur * 16384;
    const u16* vt = lds + cur * 16384 + 8192;
    const int j0 = tt * 64;

    // QK^T (S^T): A = K rows (j), B = Q cols (q)
    f32x16 sc0 = {}, sc1 = {};
#pragma unroll
    for (int kk = 0; kk < 8; ++kk) {
      const int row0 = l31;
      s16x8 kf0 = ldfrag(kt + row0 * 128 + (((kk * 2 + hi) ^ (row0 & 15)) * 8));
      sc0 = mfma32(kf0, qf[kk], sc0);
      const int row1 = 32 + l31;
      s16x8 kf1 = ldfrag(kt + row1 * 128 + (((kk * 2 + hi) ^ (row1 & 15)) * 8));
      sc1 = mfma32(kf1, qf[kk], sc1);
    }

    // mask + online softmax (lane-local row: q = l31-mapped, j spread over regs+hi)
    float p[2][16];
    const bool domask = (j0 + 63) >= (qb + SC);
    float tmax = -1e30f;
#pragma unroll
    for (int r = 0; r < 16; ++r) {
      float v0 = sc0[r], v1 = sc1[r];
      if (domask) {
        const int jl = (r & 3) + 8 * (r >> 2) + 4 * hi;
        if (j0 + jl >= q + SC) v0 = -1e30f;
        if (j0 + 32 + jl >= q + SC) v1 = -1e30f;
      }
      p[0][r] = v0; p[1][r] = v1;
      tmax = fmaxf(tmax, fmaxf(v0, v1));
    }
    tmax = fmaxf(tmax, __shfl_xor(tmax, 32, 64));
    if (tmax > mrow + 8.f) {  // defer-max: skip rescale when max barely grows
      const float soo = __expf(mrow - tmax);
      mrow = tmax;
      lrow *= soo;
#pragma unroll
      for (int dt = 0; dt < 4; ++dt)
#pragma unroll
        for (int r = 0; r < 16; ++r) o[dt][r] *= soo;
    }
    float rs = 0.f;
#pragma unroll
    for (int jt = 0; jt < 2; ++jt)
#pragma unroll
      for (int r = 0; r < 16; ++r) {
        const float e = __expf(p[jt][r] - mrow);
        p[jt][r] = e;
        rs += e;
      }
    rs += __shfl_xor(rs, 32, 64);
    lrow += rs;

    // pack P quads to bf16 pairs: pk[jt][g][pair] covers j = jt*32 + 8g + 4hi + {0..3}
    uint32_t pk[2][4][2];
#pragma unroll
    for (int jt = 0; jt < 2; ++jt)
#pragma unroll
      for (int g = 0; g < 4; ++g) {
        pk[jt][g][0] = (uint32_t)bf16rn(p[jt][g * 4 + 0]) |
                       ((uint32_t)bf16rn(p[jt][g * 4 + 1]) << 16);
        pk[jt][g][1] = (uint32_t)bf16rn(p[jt][g * 4 + 2]) |
                       ((uint32_t)bf16rn(p[jt][g * 4 + 3]) << 16);
      }

    // PV: per kt build B-frag (P^T, k = j in [kt*16, kt*16+16)) then 4 dt MFMAs
#pragma unroll
    for (int kt = 0; kt < 4; ++kt) {
      const int jts = kt >> 1;
      const int gA = (2 * kt) & 3, gB = (2 * kt + 1) & 3;
      // hi==0 sends its quad idx 4kt+2 (g=gB); hi==1 sends quad idx 4kt+1 (g=gA)
      uint32_t S0 = hi ? pk[jts][gA][0] : pk[jts][gB][0];
      uint32_t S1 = hi ? pk[jts][gA][1] : pk[jts][gB][1];
      uint32_t R0 = __shfl_xor(S0, 32, 64);
      uint32_t R1 = __shfl_xor(S1, 32, 64);
      // local: hi==0 quad 4kt (g=gA); hi==1 quad 4kt+3 (g=gB)
      uint32_t L0 = hi ? pk[jts][gB][0] : pk[jts][gA][0];
      uint32_t L1 = hi ? pk[jts][gB][1] : pk[jts][gA][1];
      union { uint32_t u[4]; s16x8 v; } pf;
      pf.u[0] = hi ? R0 : L0;
      pf.u[1] = hi ? R1 : L1;
      pf.u[2] = hi ? L0 : R0;
      pf.u[3] = hi ? L1 : R1;
#pragma unroll
      for (int dt = 0; dt < 4; ++dt) {
        const int d = dt * 32 + l31;
        s16x8 vf = ldfrag(vt + d * 64 + (((2 * kt + hi) ^ (d & 7)) * 8));
        o[dt] = mfma32(vf, pf.v, o[dt]);
      }
    }
    __syncthreads();  // drains vmcnt (next tile staged) + gates buffer reuse
  }

  // partials: op[sp][bh][q][d] f32, ml[sp][bh][q] = (m, l)
  float* opb = op + (((size_t)sp * 32 + bh) * SN + q) * DK;
#pragma unroll
  for (int dt = 0; dt < 4; ++dt)
#pragma unroll
    for (int g = 0; g < 4; ++g) {
      float4 vv;
      vv.x = o[dt][g * 4 + 0]; vv.y = o[dt][g * 4 + 1];
      vv.z = o[dt][g * 4 + 2]; vv.w = o[dt][g * 4 + 3];
      *(float4*)(opb + dt * 32 + 8 * g + 4 * hi) = vv;
    }
  if (hi == 0) {
    float2 mv; mv.x = mrow; mv.y = lrow;
    *(float2*)(ml + (((size_t)sp * 32 + bh) * SN + q) * 2) = mv;
  }
}

// ---------------- combine: merge 2 KV-split partials -> att (bf16) ----------------
__global__ void combine_kernel(const float* __restrict__ op, const float* __restrict__ ml,
                               u16* __restrict__ att) {
  const int idx = blockIdx.x * 256 + threadIdx.x;  // < 32*1024*32
  const int d4 = idx & 31;
  const int qq = (idx >> 5) & 1023;
  const int bh = idx >> 15;
  const size_t rq = (size_t)bh * SN + qq;
  const float2 ml0 = *(const float2*)(ml + rq * 2);
  const float2 ml1 = *(const float2*)(ml + (rq + 32 * (size_t)SN) * 2);
  const float ms = fmaxf(ml0.x, ml1.x);
  const float w0 = __expf(ml0.x - ms), w1 = __expf(ml1.x - ms);
  const float inv = 1.0f / (ml0.y * w0 + ml1.y * w1);
  const float4 a = *(const float4*)(op + rq * DK + d4 * 4);
  const float4 c = *(const float4*)(op + (rq + 32 * (size_t)SN) * DK + d4 * 4);
  ushort4 r;
  r.x = bf16rn((a.x * w0 + c.x * w1) * inv);
  r.y = bf16rn((a.y * w0 + c.y * w1) * inv);
  r.z = bf16rn((a.z * w0 + c.z * w1) * inv);
  r.w = bf16rn((a.w * w0 + c.w * w1) * inv);
  const int bb = bh >> 4, hh = bh & 15;
  *(ushort4*)(att + ((size_t)bb * SN + qq) * DM + hh * DK + d4 * 4) = r;
}

// ---------------- host ----------------
extern "C" void kernel_launch(void* const* d_in, const int* in_sizes, int n_in,
                              void* d_out, int out_size, void* d_ws, size_t ws_size,
                              hipStream_t stream) {
  const float* x     = (const float*)d_in[0];
  const float* cache = (const float*)d_in[1];
  const float* Wq = (const float*)d_in[2];
  const float* bq = (const float*)d_in[3];
  const float* Wk = (const float*)d_in[4];
  const float* bk = (const float*)d_in[5];
  const float* Wv = (const float*)d_in[6];
  const float* bv = (const float*)d_in[7];
  const float* Wo = (const float*)d_in[8];
  const float* bo = (const float*)d_in[9];

  float* out = (float*)d_out;
  float* cacheK = out + (size_t)2 * SN * DM;
  float* cacheV = cacheK + (size_t)2 * NH * ST * DK;

  char* ws = (char*)d_ws;
  u16* x_hi  = (u16*)(ws + 0);
  u16* wk_hi = (u16*)(ws + 8388608ull);
  u16* wv_hi = (u16*)(ws + 16777216ull);
  u16* wo_hi = (u16*)(ws + 25165824ull);
  u16* q_bf  = (u16*)(ws + 33554432ull);
  u16* k_all = (u16*)(ws + 41943040ull);   // 33,554,432 B
  u16* v_t   = (u16*)(ws + 75497472ull);   // 33,554,432 B
  u16* x_lo  = (u16*)(ws + 109051904ull);
  u16* wq_hi = (u16*)(ws + 117440512ull);
  u16* wk_lo = (u16*)(ws + 125829120ull);
  u16* wv_lo = (u16*)(ws + 134217728ull);  // ends 142,606,336
  // dead-after-gemm0 reuse:
  float* op = (float*)(ws + 109051904ull); // 33,554,432 B (x_lo..wv_lo region)
  float* ml = (float*)(ws + 8388608ull);   // 524,288 B (wk_hi region)
  u16* att  = x_hi;                        // 8,388,608 B (x_hi region)

  const int W4 = 2048 * 2048 / 4;
  pack_kernel<<<2048, 256, 0, stream>>>(x,  x_hi,  x_lo,  W4);
  pack_kernel<<<2048, 256, 0, stream>>>(Wk, wk_hi, wk_lo, W4);
  pack_kernel<<<2048, 256, 0, stream>>>(Wv, wv_hi, wv_lo, W4);
  pack_kernel<<<2048, 256, 0, stream>>>(Wq, wq_hi, nullptr, W4);
  pack_kernel<<<2048, 256, 0, stream>>>(Wo, wo_hi, nullptr, W4);
  cache_k_kernel<<<4096, 256, 0, stream>>>(cache, cacheK, k_all);
  cache_v_kernel<<<dim3(SC / 64, NH, 2), 256, 0, stream>>>(
      cache + (size_t)2 * NH * SC * DK, cacheV, v_t);
  gemm_kernel<0><<<dim3(16, 48), 256, 0, stream>>>(
      x_hi, x_lo, wq_hi, wk_hi, wk_lo, wv_hi, wv_lo,
      bq, bk, bv, q_bf, cacheK, k_all, cacheV, v_t, nullptr);
  attn_kernel<<<dim3(8, NH, 4), 256, 0, stream>>>(q_bf, k_all, v_t, op, ml);
  combine_kernel<<<4096, 256, 0, stream>>>(op, ml, att);
  gemm_kernel<1><<<dim3(16, 16), 256, 0, stream>>>(
      att, nullptr, wo_hi, nullptr, nullptr, nullptr, nullptr,
      bo, nullptr, nullptr, nullptr, nullptr, nullptr, nullptr, nullptr, out);
}